// Round 3
// baseline (3557.809 us; speedup 1.0000x reference)
//
#include <hip/hip_runtime.h>
#include <hip/hip_fp16.h>

// TanhFixedPointLayer: z_{k+1} = tanh(z_k @ W^T + x), z0 = 0, 50 iterations.
// Fused persistent-tile: block owns 64 rows; z in LDS (f16, frag-packed);
// x + accumulators in registers; W pre-packed in MFMA A-frag order, streamed
// from L2 every iteration with DEPTH-3 rotating register prefetch (12 b128 in
// flight per wave -> 96 KB/CU, saturating per-CU L2 BW ~56 B/cyc against
// 200-900 cyc L2/MALL latency). No barriers inside the ks-loop.

#define DDIM  512
#define MTILE 64
#define NITER 50     // z1 = tanh(x) counts as iteration 1; 49 MFMA iterations

typedef _Float16 half8  __attribute__((ext_vector_type(8)));
typedef _Float16 half4v __attribute__((ext_vector_type(4)));
typedef float    float4v __attribute__((ext_vector_type(4)));

__device__ __forceinline__ float fast_tanh(float t) {
    // tanh(t) = 1 - 2/(exp(2t)+1); exp(2t) = 2^(t*2*log2(e)); exact +-1 at sat.
    float e = __builtin_amdgcn_exp2f(t * 2.8853900817779268f);
    return 1.0f - 2.0f * __builtin_amdgcn_rcpf(e + 1.0f);
}

// z LDS layout = frag-packed: B-frag (ks, mf) for lane L is the 16B chunk at
// ((ks*4 + mf)*64 + L)*8 halves. Element (m,k) sits at:
__device__ __forceinline__ int zaddr(int m, int k) {
    return (((k >> 5) * 4 + (m >> 4)) << 9) + (((m & 15) + (((k >> 3) & 3) << 4)) << 3) + (k & 7);
}

// ---- prep: pack W (fp32 [512][512]) into f16 MFMA A-frag order.
// Frag (ks, nf) block = 64 lanes x 16B: lane L holds
//   W[nf*16 + (L&15)][ks*32 + (L>>4)*8 + j], j=0..7
__global__ void wpack_kernel(const float* __restrict__ W, _Float16* __restrict__ Wpk) {
    int gid  = blockIdx.x * blockDim.x + threadIdx.x;   // 0..32767
    int ks   = gid >> 11;
    int nf   = (gid >> 6) & 31;
    int lane = gid & 63;
    int row  = nf * 16 + (lane & 15);
    int col  = ks * 32 + (lane >> 4) * 8;
    const float* src = W + row * DDIM + col;
    half8 h;
#pragma unroll
    for (int j = 0; j < 8; ++j) h[j] = (_Float16)src[j];
    *(half8*)(Wpk + (size_t)gid * 8) = h;
}

__global__ __launch_bounds__(512, 2)
void fixpoint_kernel(const float* __restrict__ x,
                     const _Float16* __restrict__ Wpk,
                     float* __restrict__ out) {
    __shared__ __align__(16) _Float16 zsh[MTILE * DDIM];   // 64 KB, frag-packed

    const int tid  = threadIdx.x;
    const int lane = tid & 63;
    const int wid  = tid >> 6;          // 0..7, each wave owns 64 n-columns
    const int l15  = lane & 15;
    const int quad = lane >> 4;
    const int nf0  = wid * 4;           // first of this wave's 4 n-frags

    const int row_blk = blockIdx.x * MTILE;
    const half8* Wv = (const half8*)Wpk;

    // ---- x in registers at this lane's C/D slots:
    float4 xr[4][4];
#pragma unroll
    for (int f = 0; f < 4; ++f) {
        int n = (nf0 + f) * 16 + quad * 4;
#pragma unroll
        for (int mf = 0; mf < 4; ++mf) {
            xr[f][mf] = *(const float4*)(x + (size_t)(row_blk + mf * 16 + l15) * DDIM + n);
        }
    }

    // ---- z1 = tanh(x) -> LDS (b64 contiguous writes)
#pragma unroll
    for (int f = 0; f < 4; ++f) {
        int n = (nf0 + f) * 16 + quad * 4;
#pragma unroll
        for (int mf = 0; mf < 4; ++mf) {
            int m = mf * 16 + l15;
            half4v h;
            h[0] = (_Float16)fast_tanh(xr[f][mf].x);
            h[1] = (_Float16)fast_tanh(xr[f][mf].y);
            h[2] = (_Float16)fast_tanh(xr[f][mf].z);
            h[3] = (_Float16)fast_tanh(xr[f][mf].w);
            *(half4v*)(zsh + zaddr(m, n)) = h;
        }
    }
    __syncthreads();

    // ---- depth-3 rotating W prefetch: preload slots for ks = 0,1,2
    half8 aw[4][4];   // [slot = ks & 3][frag]
    half8 bz[2][4];   // [slot = ks & 1][mfrag]
#pragma unroll
    for (int p = 0; p < 3; ++p)
#pragma unroll
        for (int f = 0; f < 4; ++f)
            aw[p][f] = Wv[(p * 32 + nf0 + f) * 64 + lane];

    for (int it = 0; it < NITER - 1; ++it) {
        float4v acc[4][4];
#pragma unroll
        for (int f = 0; f < 4; ++f)
#pragma unroll
            for (int mf = 0; mf < 4; ++mf) acc[f][mf] = (float4v){0.f, 0.f, 0.f, 0.f};

        // z slot 0 (valid: after init-sync or epilogue-sync)
#pragma unroll
        for (int mf = 0; mf < 4; ++mf)
            bz[0][mf] = *(const half8*)(zsh + (mf * 64 + lane) * 8);

#pragma unroll
        for (int ks = 0; ks < 16; ++ks) {
            // W prefetch 3 steps ahead, wrapping into the NEXT iteration
            // (W is iteration-invariant, so the pipeline never restarts)
            {
                int kk = (ks + 3) & 15;
#pragma unroll
                for (int f = 0; f < 4; ++f)
                    aw[(ks + 3) & 3][f] = Wv[(kk * 32 + nf0 + f) * 64 + lane];
            }
            if (ks < 15) {
#pragma unroll
                for (int mf = 0; mf < 4; ++mf)
                    bz[(ks + 1) & 1][mf] = *(const half8*)(zsh + (((ks + 1) * 4 + mf) * 64 + lane) * 8);
            }
#pragma unroll
            for (int f = 0; f < 4; ++f)
#pragma unroll
                for (int mf = 0; mf < 4; ++mf)
                    acc[f][mf] = __builtin_amdgcn_mfma_f32_16x16x32_f16(aw[ks & 3][f], bz[ks & 1][mf], acc[f][mf], 0, 0, 0);
        }
        __syncthreads();   // all reads of z_k done

        if (it < NITER - 2) {
            // z_{k+1} = tanh(acc + x) -> LDS, contiguous b64 per frag
#pragma unroll
            for (int f = 0; f < 4; ++f) {
                int n = (nf0 + f) * 16 + quad * 4;
#pragma unroll
                for (int mf = 0; mf < 4; ++mf) {
                    int m = mf * 16 + l15;
                    half4v h;
                    h[0] = (_Float16)fast_tanh(acc[f][mf][0] + xr[f][mf].x);
                    h[1] = (_Float16)fast_tanh(acc[f][mf][1] + xr[f][mf].y);
                    h[2] = (_Float16)fast_tanh(acc[f][mf][2] + xr[f][mf].z);
                    h[3] = (_Float16)fast_tanh(acc[f][mf][3] + xr[f][mf].w);
                    *(half4v*)(zsh + zaddr(m, n)) = h;
                }
            }
            __syncthreads();
        } else {
            // final iteration: store z50 straight from registers (fp32)
#pragma unroll
            for (int f = 0; f < 4; ++f) {
                int n = (nf0 + f) * 16 + quad * 4;
#pragma unroll
                for (int mf = 0; mf < 4; ++mf) {
                    float4 v;
                    v.x = fast_tanh(acc[f][mf][0] + xr[f][mf].x);
                    v.y = fast_tanh(acc[f][mf][1] + xr[f][mf].y);
                    v.z = fast_tanh(acc[f][mf][2] + xr[f][mf].z);
                    v.w = fast_tanh(acc[f][mf][3] + xr[f][mf].w);
                    *(float4*)(out + (size_t)(row_blk + mf * 16 + l15) * DDIM + n) = v;
                }
            }
        }
    }
}

extern "C" void kernel_launch(void* const* d_in, const int* in_sizes, int n_in,
                              void* d_out, int out_size, void* d_ws, size_t ws_size,
                              hipStream_t stream) {
    const float* x = (const float*)d_in[0];   // [65536, 512] fp32
    const float* W = (const float*)d_in[1];   // [512, 512] fp32
    _Float16* Wpk = (_Float16*)d_ws;          // 512 KB packed f16 W
    float* out = (float*)d_out;

    wpack_kernel<<<128, 256, 0, stream>>>(W, Wpk);
    fixpoint_kernel<<<65536 / MTILE, 512, 0, stream>>>(x, Wpk, out);
}